// Round 10
// baseline (214.515 us; speedup 1.0000x reference)
//
#include <hip/hip_runtime.h>
#include <hip/hip_bf16.h>
#include <cstdint>

typedef __bf16 bf16_t;
typedef __bf16 bf16x4 __attribute__((ext_vector_type(4)));
typedef __bf16 bf16x8 __attribute__((ext_vector_type(8)));
typedef float floatx4 __attribute__((ext_vector_type(4)));
typedef float floatx16 __attribute__((ext_vector_type(16)));
typedef unsigned int u32x4 __attribute__((ext_vector_type(4)));

#define NB 4
#define NH 12
#define SEQ 2048
#define DM 768
#define LOG2E 1.44269504088896340736f

// async global->LDS, 16B per lane; LDS dest is wave-uniform base + lane*16
__device__ __forceinline__ void gload_lds16(const bf16_t* g, bf16_t* l) {
  auto gp = reinterpret_cast<const __attribute__((address_space(1))) uint32_t*>(
      reinterpret_cast<uintptr_t>(g));
  auto lp = reinterpret_cast<__attribute__((address_space(3))) uint32_t*>(
      reinterpret_cast<uintptr_t>(l));
  __builtin_amdgcn_global_load_lds(gp, lp, 16, 0, 0);
}

// pack two f32 -> one dword of 2 bf16 (lo = a, hi = b)
__device__ __forceinline__ unsigned int pack2(float a, float b) {
  bf16_t x = (bf16_t)a, y = (bf16_t)b;
  unsigned short ux = __builtin_bit_cast(unsigned short, x);
  unsigned short uy = __builtin_bit_cast(unsigned short, y);
  return (unsigned int)ux | ((unsigned int)uy << 16);
}

// ---------------------------------------------------------------- fused prep
// blockIdx ranges: [0,6144) cvt x->xb; [6144,7872) w_qkv transpose (72x24);
// [7872,8448) w_proj transpose (24x24). One launch instead of three.
__global__ __launch_bounds__(256) void prep_kernel(
    const float* __restrict__ x, bf16_t* __restrict__ xb,
    const float* __restrict__ wqkv, bf16_t* __restrict__ wqkvT,
    const float* __restrict__ wproj, bf16_t* __restrict__ wprojT) {
  const int bid = blockIdx.x;
  const int tid = threadIdx.x;
  if (bid < 6144) {
    int i = (bid * 256 + tid) * 4;
    float4 v = *(const float4*)(x + i);
    bf16x4 hh;
    hh[0] = (bf16_t)v.x; hh[1] = (bf16_t)v.y; hh[2] = (bf16_t)v.z; hh[3] = (bf16_t)v.w;
    *(bf16x4*)(xb + i) = hh;
    return;
  }
  const float* in;
  bf16_t* out;
  int N, nb, kb;
  if (bid < 7872) {
    int t = bid - 6144;
    in = wqkv; out = wqkvT; N = 2304;
    nb = (t % 72) * 32; kb = (t / 72) * 32;
  } else {
    int t = bid - 7872;
    in = wproj; out = wprojT; N = 768;
    nb = (t % 24) * 32; kb = (t / 24) * 32;
  }
  const int K = 768;
  __shared__ float tile[32][33];
  int tx = tid & 31, ty = tid >> 5;
#pragma unroll
  for (int r = ty; r < 32; r += 8)
    tile[r][tx] = in[(size_t)(kb + r) * N + nb + tx];
  __syncthreads();
#pragma unroll
  for (int r = ty; r < 32; r += 8)
    out[(size_t)(nb + r) * K + kb + tx] = (bf16_t)tile[tx][r];
}

// ---------------------------------------------------------------- QKV GEMM (m97 structure, BK=32 — R5 proven)
__global__ __launch_bounds__(256) void gemm_qkv_kernel(
    const bf16_t* __restrict__ A, const bf16_t* __restrict__ BT,
    const float* __restrict__ bias,
    bf16_t* __restrict__ Qo, bf16_t* __restrict__ Ko, bf16_t* __restrict__ Vo) {
  const int K = 768;
  __shared__ __align__(16) bf16_t As[128][32];
  __shared__ __align__(16) bf16_t Bs[128][32];
  const int m0 = blockIdx.x * 128, n0 = blockIdx.y * 128;
  const int tid = threadIdx.x;
  const int w = tid >> 6, lane = tid & 63, quad = lane >> 4, l16 = lane & 15;
  const int wm = w >> 1, wn = w & 1;
  const int ldrow = w * 32;
  const int grow = lane >> 2;
  const int gcol = (lane & 3) * 8;

  floatx4 acc[4][4];
#pragma unroll
  for (int mt = 0; mt < 4; mt++)
#pragma unroll
    for (int nt = 0; nt < 4; nt++) acc[mt][nt] = (floatx4)(0.f);

  const bf16_t* ga0 = A + (size_t)(m0 + ldrow) * K;
  const bf16_t* gb0 = BT + (size_t)(n0 + ldrow) * K;

  for (int k0 = 0; k0 < K; k0 += 32) {
    __syncthreads();
    gload_lds16(ga0 + (size_t)grow * K + k0 + gcol,        &As[ldrow][0]);
    gload_lds16(ga0 + (size_t)(grow + 16) * K + k0 + gcol, &As[ldrow + 16][0]);
    gload_lds16(gb0 + (size_t)grow * K + k0 + gcol,        &Bs[ldrow][0]);
    gload_lds16(gb0 + (size_t)(grow + 16) * K + k0 + gcol, &Bs[ldrow + 16][0]);
    __syncthreads();
    bf16x8 af[4], bfr[4];
#pragma unroll
    for (int mt = 0; mt < 4; mt++)
      af[mt] = *(const bf16x8*)&As[wm * 64 + mt * 16 + l16][quad * 8];
#pragma unroll
    for (int nt = 0; nt < 4; nt++)
      bfr[nt] = *(const bf16x8*)&Bs[wn * 64 + nt * 16 + l16][quad * 8];
#pragma unroll
    for (int mt = 0; mt < 4; mt++)
#pragma unroll
      for (int nt = 0; nt < 4; nt++)
        acc[mt][nt] = __builtin_amdgcn_mfma_f32_16x16x32_bf16(af[mt], bfr[nt], acc[mt][nt], 0, 0, 0);
  }

  const int which = n0 / 768;
  const int rem0 = n0 % 768;
  bf16_t* dst = which == 0 ? Qo : (which == 1 ? Ko : Vo);
  const float qscale = which == 0 ? (0.125f * LOG2E) : 1.0f;
#pragma unroll
  for (int nt = 0; nt < 4; nt++) {
    const int cc = wn * 64 + nt * 16 + l16;
    const int rem = rem0 + cc;
    const int h = rem >> 6, hd = rem & 63;
    const float bv = bias[n0 + cc];
#pragma unroll
    for (int mt = 0; mt < 4; mt++)
#pragma unroll
      for (int r = 0; r < 4; r++) {
        const int gr = m0 + wm * 64 + mt * 16 + quad * 4 + r;
        const int bb = gr >> 11, s = gr & 2047;
        const float val = (acc[mt][nt][r] + bv) * qscale;
        dst[((size_t)((bb * NH + h) * SEQ + s)) * 64 + hd] = (bf16_t)val;
      }
  }
}

// ---------------------------------------------------------------- V transpose
__global__ __launch_bounds__(256) void vtrans_kernel(const bf16_t* __restrict__ V,
                                                     bf16_t* __restrict__ Vt) {
  __shared__ bf16_t tile[64][66];
  int bh = blockIdx.y, s0 = blockIdx.x * 64;
  int tid = threadIdx.x;
  int r = tid >> 4, c4 = (tid & 15) * 4;
  const bf16_t* src = V + (size_t)bh * SEQ * 64;
#pragma unroll
  for (int rr = r; rr < 64; rr += 16)
    *(bf16x4*)&tile[rr][c4] = *(const bf16x4*)&src[(size_t)(s0 + rr) * 64 + c4];
  __syncthreads();
  bf16_t* dst = Vt + (size_t)bh * 64 * SEQ;
#pragma unroll
  for (int hd = r; hd < 64; hd += 16) {
    bf16x4 o;
    o[0] = tile[c4 + 0][hd]; o[1] = tile[c4 + 1][hd];
    o[2] = tile[c4 + 2][hd]; o[3] = tile[c4 + 3][hd];
    *(bf16x4*)&dst[(size_t)hd * SEQ + s0 + c4] = o;
  }
}

// ---------------------------------------------------------------- flash attention
// R9 inner math (swapped-QK^T 32x32, triple-buffer LDS K/V, pre-swizzled src +
// XOR reads, T13 defer-max, ones-MFMA l-sum), restructured to 8 WAVES/BLOCK:
// 512 threads, 256 q-rows/block, grid (48,8). Each staged K/V tile now feeds
// 8 waves -> total staged-tile iterations 13056 -> 6912 (-47%), barriers
// likewise; stage is 1 K + 1 V load/thread (vmcnt 4 -> 2). Avg waves/CU
// unchanged -> isolates sync/stage overhead as the variable.
__global__ __launch_bounds__(512, 4) void attn_kernel(
    const bf16_t* __restrict__ Q, const bf16_t* __restrict__ Kg,
    const bf16_t* __restrict__ Vt, bf16_t* __restrict__ Out) {
  __shared__ __align__(16) bf16_t Ks[3][64 * 64];  // 8KB per buf
  __shared__ __align__(16) bf16_t Vs[3][64 * 64];  // 8KB per buf (V^T layout)
  const int tid = threadIdx.x;
  const int w = tid >> 6, lane = tid & 63;
  const int l31 = lane & 31, hi = lane >> 5;
  const int bh = blockIdx.x;
  const int b = bh / NH, h = bh % NH;
  const int qt = (int)(gridDim.y - 1) - (int)blockIdx.y;  // heaviest first
  const int r0 = qt * 256 + w * 32;
  const int qrow = r0 + l31;
  const bf16_t* Qp = Q + (size_t)bh * SEQ * 64;
  const bf16_t* Kp = Kg + (size_t)bh * SEQ * 64;
  const bf16_t* Vp = Vt + (size_t)bh * 64 * SEQ;

  // Q fragment (B-operand): qf[kc][e] = Q[qrow][kc*16 + hi*8 + e]
  bf16x8 qf[4];
#pragma unroll
  for (int kc = 0; kc < 4; kc++)
    qf[kc] = *(const bf16x8*)&Qp[(size_t)qrow * 64 + kc * 16 + hi * 8];

  bf16x8 ones;
#pragma unroll
  for (int j = 0; j < 8; j++) ones[j] = (bf16_t)1.0f;

  float m_i = -1e30f;
  floatx16 accT[2];  // O^T: accT[dt][reg] = O[qrow][dt*32 + rowfn(reg,hi)]
  accT[0] = (floatx16)(0.f);
  accT[1] = (floatx16)(0.f);
  floatx16 zl = (floatx16)(0.f);  // l-sum via ones-MFMA (all rows identical)

  const int nt_w = (r0 >> 6) + 1;          // this wave's tile count
  const int ntmax = 4 * qt + 4;            // block's max tile count (w=7)

  // staging: one round, 512 threads x 16B = 8KB = full buffer.
  // byte off = tid*16 -> row = tid>>3, col slot = tid&7; source pre-swizzled.
  const int srow = tid >> 3;
  const int scolb = ((tid & 7) ^ (srow & 7)) << 4;  // bytes

  auto stage = [&](int buf, int kt) {
    const int kbase = kt * 64;
    gload_lds16(Kp + (size_t)(kbase + srow) * 64 + (scolb >> 1), &Ks[buf][w * 512]);
    gload_lds16(Vp + (size_t)srow * SEQ + kbase + (scolb >> 1), &Vs[buf][w * 512]);
  };

  const int swz = (l31 & 7) << 4;  // read-side XOR (row&7 == l31&7 for all frags)

  stage(0, 0);  // prologue: tile 0 -> buf 0 (2 loads in flight)

  int cur = 0;
  for (int kt = 0; kt < ntmax; kt++) {
    const int nxt = (cur == 2) ? 0 : cur + 1;
    if (kt + 1 < ntmax) {
      stage(nxt, kt + 1);
      asm volatile("s_waitcnt vmcnt(2)" ::: "memory");  // buf[cur] landed
    } else {
      asm volatile("s_waitcnt vmcnt(0)" ::: "memory");
    }
    __builtin_amdgcn_s_barrier();  // all waves' stage of buf[cur] visible

    if (kt < nt_w) {
      const int kbase = kt * 64;
      const bf16_t* Kb = Ks[cur];
      const bf16_t* Vb = Vs[cur];
      // ---- QK^T (swapped): st[kt2][r] = S[qrow][kbase+kt2*32+(r&3)+8*(r>>2)+4*hi]
      floatx16 st[2];
#pragma unroll
      for (int kt2 = 0; kt2 < 2; kt2++) {
        const int row = kt2 * 32 + l31;
        floatx16 z = (floatx16)(0.f);
#pragma unroll
        for (int kc = 0; kc < 4; kc++) {
          bf16x8 kfr = *(const bf16x8*)&Kb[row * 64 + (((kc * 32 + hi * 16) ^ swz) >> 1)];
          z = __builtin_amdgcn_mfma_f32_32x32x16_bf16(kfr, qf[kc], z, 0, 0, 0);
        }
        st[kt2] = z;
      }
      // ---- causal mask (only on this wave's last tile)
      if (kt == nt_w - 1) {
#pragma unroll
        for (int kt2 = 0; kt2 < 2; kt2++)
#pragma unroll
          for (int r = 0; r < 16; r++) {
            int key = kbase + kt2 * 32 + (r & 3) + 8 * (r >> 2) + 4 * hi;
            if (key > qrow) st[kt2][r] = -1e30f;
          }
      }
      // ---- online softmax (exp2 domain), T13 defer-max
      float mloc = -1e30f;
#pragma unroll
      for (int kt2 = 0; kt2 < 2; kt2++)
#pragma unroll
        for (int r = 0; r < 16; r++) mloc = fmaxf(mloc, st[kt2][r]);
      mloc = fmaxf(mloc, __shfl_xor(mloc, 32));
      if (!__all((int)(mloc - m_i <= 8.f))) {  // rescale path (rare after tile 0)
        const float mnew = fmaxf(m_i, mloc);
        const float al = __builtin_amdgcn_exp2f(m_i - mnew);
        m_i = mnew;
#pragma unroll
        for (int r = 0; r < 16; r++) zl[r] *= al;
#pragma unroll
        for (int dt = 0; dt < 2; dt++)
#pragma unroll
          for (int r = 0; r < 16; r++) accT[dt][r] *= al;
      }
#pragma unroll
      for (int kt2 = 0; kt2 < 2; kt2++)
#pragma unroll
        for (int r = 0; r < 16; r++)
          st[kt2][r] = __builtin_amdgcn_exp2f(st[kt2][r] - m_i);  // <= 2^8
      // ---- P pack + half-wave exchange -> B-fragments; PV + l-sum MFMAs
#pragma unroll
      for (int kt2 = 0; kt2 < 2; kt2++) {
        unsigned int wds[8];
#pragma unroll
        for (int j = 0; j < 8; j++) wds[j] = pack2(st[kt2][2 * j], st[kt2][2 * j + 1]);
        unsigned int x0 = (unsigned int)__shfl_xor((int)(hi ? wds[0] : wds[2]), 32);
        unsigned int x1 = (unsigned int)__shfl_xor((int)(hi ? wds[1] : wds[3]), 32);
        unsigned int x2 = (unsigned int)__shfl_xor((int)(hi ? wds[4] : wds[6]), 32);
        unsigned int x3 = (unsigned int)__shfl_xor((int)(hi ? wds[5] : wds[7]), 32);
        u32x4 f0 = hi ? (u32x4){x0, x1, wds[2], wds[3]} : (u32x4){wds[0], wds[1], x0, x1};
        u32x4 f1 = hi ? (u32x4){x2, x3, wds[6], wds[7]} : (u32x4){wds[4], wds[5], x2, x3};
        bf16x8 pf0 = __builtin_bit_cast(bf16x8, f0);
        bf16x8 pf1 = __builtin_bit_cast(bf16x8, f1);
        zl = __builtin_amdgcn_mfma_f32_32x32x16_bf16(ones, pf0, zl, 0, 0, 0);
        zl = __builtin_amdgcn_mfma_f32_32x32x16_bf16(ones, pf1, zl, 0, 0, 0);
#pragma unroll
        for (int dt = 0; dt < 2; dt++) {
          const int vrow = dt * 32 + l31;
          bf16x8 v0 = *(const bf16x8*)&Vb[vrow * 64 + (((kt2 * 64 + hi * 16) ^ swz) >> 1)];
          bf16x8 v1 = *(const bf16x8*)&Vb[vrow * 64 + (((kt2 * 64 + 32 + hi * 16) ^ swz) >> 1)];
          accT[dt] = __builtin_amdgcn_mfma_f32_32x32x16_bf16(v0, pf0, accT[dt], 0, 0, 0);
          accT[dt] = __builtin_amdgcn_mfma_f32_32x32x16_bf16(v1, pf1, accT[dt], 0, 0, 0);
        }
      }
    }
    cur = nxt;
  }

  // ---- epilogue: lane-local divide (zl rows all identical), bf16x4 stores
  const float inv_l = 1.0f / zl[0];
#pragma unroll
  for (int dt = 0; dt < 2; dt++)
#pragma unroll
    for (int g = 0; g < 4; g++) {
      bf16x4 o;
#pragma unroll
      for (int j = 0; j < 4; j++) o[j] = (bf16_t)(accT[dt][4 * g + j] * inv_l);
      int d = dt * 32 + 8 * g + 4 * hi;
      *(bf16x4*)&Out[((size_t)(b * SEQ + qrow)) * DM + h * 64 + d] = o;
    }
}

// ---------------------------------------------------------------- out-proj GEMM (m97 structure, BK=32 — R5 proven)
__global__ __launch_bounds__(256) void gemm_proj_kernel(
    const bf16_t* __restrict__ A, const bf16_t* __restrict__ BT,
    const float* __restrict__ bias, float* __restrict__ out) {
  const int K = 768;
  __shared__ __align__(16) bf16_t As[128][32];
  __shared__ __align__(16) bf16_t Bs[128][32];
  const int m0 = blockIdx.x * 128, n0 = blockIdx.y * 128;
  const int tid = threadIdx.x;
  const int w = tid >> 6, lane = tid & 63, quad = lane >> 4, l16 = lane & 15;
  const int wm = w >> 1, wn = w & 1;
  const int ldrow = w * 32;
  const int grow = lane >> 2;
  const int gcol = (lane & 3) * 8;

  floatx4 acc[4][4];
#pragma unroll
  for (int mt = 0; mt < 4; mt++)
#pragma unroll
    for (int nt = 0; nt < 4; nt++) acc[mt][nt] = (floatx4)(0.f);

  const bf16_t* ga0 = A + (size_t)(m0 + ldrow) * K;
  const bf16_t* gb0 = BT + (size_t)(n0 + ldrow) * K;

  for (int k0 = 0; k0 < K; k0 += 32) {
    __syncthreads();
    gload_lds16(ga0 + (size_t)grow * K + k0 + gcol,        &As[ldrow][0]);
    gload_lds16(ga0 + (size_t)(grow + 16) * K + k0 + gcol, &As[ldrow + 16][0]);
    gload_lds16(gb0 + (size_t)grow * K + k0 + gcol,        &Bs[ldrow][0]);
    gload_lds16(gb0 + (size_t)(grow + 16) * K + k0 + gcol, &Bs[ldrow + 16][0]);
    __syncthreads();
    bf16x8 af[4], bfr[4];
#pragma unroll
    for (int mt = 0; mt < 4; mt++)
      af[mt] = *(const bf16x8*)&As[wm * 64 + mt * 16 + l16][quad * 8];
#pragma unroll
    for (int nt = 0; nt < 4; nt++)
      bfr[nt] = *(const bf16x8*)&Bs[wn * 64 + nt * 16 + l16][quad * 8];
#pragma unroll
    for (int mt = 0; mt < 4; mt++)
#pragma unroll
      for (int nt = 0; nt < 4; nt++)
        acc[mt][nt] = __builtin_amdgcn_mfma_f32_16x16x32_bf16(af[mt], bfr[nt], acc[mt][nt], 0, 0, 0);
  }

#pragma unroll
  for (int nt = 0; nt < 4; nt++) {
    const int gc = n0 + wn * 64 + nt * 16 + l16;
    const float bv = bias[gc];
#pragma unroll
    for (int mt = 0; mt < 4; mt++)
#pragma unroll
      for (int r = 0; r < 4; r++) {
        const int gr = m0 + wm * 64 + mt * 16 + quad * 4 + r;
        out[(size_t)gr * 768 + gc] = acc[mt][nt][r] + bv;
      }
  }
}

// ---------------------------------------------------------------- launch
extern "C" void kernel_launch(void* const* d_in, const int* in_sizes, int n_in,
                              void* d_out, int out_size, void* d_ws, size_t ws_size,
                              hipStream_t stream) {
  const float* x      = (const float*)d_in[0];
  const float* w_qkv  = (const float*)d_in[1];
  const float* b_qkv  = (const float*)d_in[2];
  const float* w_proj = (const float*)d_in[3];
  const float* b_proj = (const float*)d_in[4];
  float* out = (float*)d_out;
  char* ws = (char*)d_ws;

  // workspace layout (all 16B-aligned), total 67,633,152 B
  bf16_t* xb     = (bf16_t*)(ws + 0);         // 8192*768  bf16 (dead after gemm_qkv)
  bf16_t* wqkvT  = (bf16_t*)(ws + 12582912);  // 2304*768  bf16
  bf16_t* wprojT = (bf16_t*)(ws + 16121856);  //  768*768  bf16
  bf16_t* q      = (bf16_t*)(ws + 17301504);  // [4][12][2048][64] bf16
  bf16_t* k      = (bf16_t*)(ws + 29884416);
  bf16_t* v      = (bf16_t*)(ws + 42467328);
  bf16_t* ao     = (bf16_t*)(ws + 55050240);  // [8192][768] bf16
  bf16_t* vt     = xb;                        // aliases xb: [4][12][64][2048] bf16

  prep_kernel<<<8448, 256, 0, stream>>>(x, xb, w_qkv, wqkvT, w_proj, wprojT);
  gemm_qkv_kernel<<<dim3(64, 18), 256, 0, stream>>>(xb, wqkvT, b_qkv, q, k, v);
  vtrans_kernel<<<dim3(32, 48), 256, 0, stream>>>(v, vt);
  attn_kernel<<<dim3(48, 8), 512, 0, stream>>>(q, k, vt, ao);
  gemm_proj_kernel<<<dim3(64, 6), 256, 0, stream>>>(ao, wprojT, b_proj, out);
}

// Round 11
// 205.860 us; speedup vs baseline: 1.0420x; 1.0420x over previous
//
#include <hip/hip_runtime.h>
#include <hip/hip_bf16.h>
#include <cstdint>

typedef __bf16 bf16_t;
typedef __bf16 bf16x4 __attribute__((ext_vector_type(4)));
typedef __bf16 bf16x8 __attribute__((ext_vector_type(8)));
typedef float floatx4 __attribute__((ext_vector_type(4)));
typedef float floatx16 __attribute__((ext_vector_type(16)));
typedef unsigned int u32x4 __attribute__((ext_vector_type(4)));

#define NB 4
#define NH 12
#define SEQ 2048
#define DM 768
#define LOG2E 1.44269504088896340736f

// async global->LDS, 16B per lane; LDS dest is wave-uniform base + lane*16
__device__ __forceinline__ void gload_lds16(const bf16_t* g, bf16_t* l) {
  auto gp = reinterpret_cast<const __attribute__((address_space(1))) uint32_t*>(
      reinterpret_cast<uintptr_t>(g));
  auto lp = reinterpret_cast<__attribute__((address_space(3))) uint32_t*>(
      reinterpret_cast<uintptr_t>(l));
  __builtin_amdgcn_global_load_lds(gp, lp, 16, 0, 0);
}

// pack two f32 -> one dword of 2 bf16 (lo = a, hi = b)
__device__ __forceinline__ unsigned int pack2(float a, float b) {
  bf16_t x = (bf16_t)a, y = (bf16_t)b;
  unsigned short ux = __builtin_bit_cast(unsigned short, x);
  unsigned short uy = __builtin_bit_cast(unsigned short, y);
  return (unsigned int)ux | ((unsigned int)uy << 16);
}

// ---------------------------------------------------------------- fused prep
// blockIdx ranges: [0,6144) cvt x->xb; [6144,7872) w_qkv transpose (72x24);
// [7872,8448) w_proj transpose (24x24). One launch instead of three (R10: -5us).
__global__ __launch_bounds__(256) void prep_kernel(
    const float* __restrict__ x, bf16_t* __restrict__ xb,
    const float* __restrict__ wqkv, bf16_t* __restrict__ wqkvT,
    const float* __restrict__ wproj, bf16_t* __restrict__ wprojT) {
  const int bid = blockIdx.x;
  const int tid = threadIdx.x;
  if (bid < 6144) {
    int i = (bid * 256 + tid) * 4;
    float4 v = *(const float4*)(x + i);
    bf16x4 hh;
    hh[0] = (bf16_t)v.x; hh[1] = (bf16_t)v.y; hh[2] = (bf16_t)v.z; hh[3] = (bf16_t)v.w;
    *(bf16x4*)(xb + i) = hh;
    return;
  }
  const float* in;
  bf16_t* out;
  int N, nb, kb;
  if (bid < 7872) {
    int t = bid - 6144;
    in = wqkv; out = wqkvT; N = 2304;
    nb = (t % 72) * 32; kb = (t / 72) * 32;
  } else {
    int t = bid - 7872;
    in = wproj; out = wprojT; N = 768;
    nb = (t % 24) * 32; kb = (t / 24) * 32;
  }
  const int K = 768;
  __shared__ float tile[32][33];
  int tx = tid & 31, ty = tid >> 5;
#pragma unroll
  for (int r = ty; r < 32; r += 8)
    tile[r][tx] = in[(size_t)(kb + r) * N + nb + tx];
  __syncthreads();
#pragma unroll
  for (int r = ty; r < 32; r += 8)
    out[(size_t)(nb + r) * K + kb + tx] = (bf16_t)tile[tx][r];
}

// ---------------------------------------------------------------- QKV GEMM
// m97 tiling (128x128, BK=32) upgraded from 1-phase (stage; drain; compute —
// tile latency fully exposed x24) to the R5-attn-proven schedule: TRIPLE-
// buffered LDS, stage(next) issued BEFORE compute(current), counted vmcnt(4),
// ONE s_barrier per tile. Race-free per R5 analysis: barrier(j+1) separates
// compute(buf) in iter j from re-stage of that buf issued in iter j+2.
__global__ __launch_bounds__(256) void gemm_qkv_kernel(
    const bf16_t* __restrict__ A, const bf16_t* __restrict__ BT,
    const float* __restrict__ bias,
    bf16_t* __restrict__ Qo, bf16_t* __restrict__ Ko, bf16_t* __restrict__ Vo) {
  const int K = 768;
  const int NT = 24;  // K / 32
  __shared__ __align__(16) bf16_t As[3][128 * 32];
  __shared__ __align__(16) bf16_t Bs[3][128 * 32];
  const int m0 = blockIdx.x * 128, n0 = blockIdx.y * 128;
  const int tid = threadIdx.x;
  const int w = tid >> 6, lane = tid & 63, quad = lane >> 4, l16 = lane & 15;
  const int wm = w >> 1, wn = w & 1;
  const int ldrow = w * 32;
  const int grow = lane >> 2;
  const int gcol = (lane & 3) * 8;

  floatx4 acc[4][4];
#pragma unroll
  for (int mt = 0; mt < 4; mt++)
#pragma unroll
    for (int nt = 0; nt < 4; nt++) acc[mt][nt] = (floatx4)(0.f);

  const bf16_t* ga0 = A + (size_t)(m0 + ldrow) * K;
  const bf16_t* gb0 = BT + (size_t)(n0 + ldrow) * K;

  auto stage = [&](int buf, int k0) {
    gload_lds16(ga0 + (size_t)grow * K + k0 + gcol,        &As[buf][ldrow * 32]);
    gload_lds16(ga0 + (size_t)(grow + 16) * K + k0 + gcol, &As[buf][(ldrow + 16) * 32]);
    gload_lds16(gb0 + (size_t)grow * K + k0 + gcol,        &Bs[buf][ldrow * 32]);
    gload_lds16(gb0 + (size_t)(grow + 16) * K + k0 + gcol, &Bs[buf][(ldrow + 16) * 32]);
  };

  stage(0, 0);
  int cur = 0;
  for (int t = 0; t < NT; t++) {
    const int nxt = (cur == 2) ? 0 : cur + 1;
    if (t + 1 < NT) {
      stage(nxt, (t + 1) * 32);
      asm volatile("s_waitcnt vmcnt(4)" ::: "memory");  // buf[cur] landed
    } else {
      asm volatile("s_waitcnt vmcnt(0)" ::: "memory");
    }
    __builtin_amdgcn_s_barrier();

    bf16x8 af[4], bfr[4];
#pragma unroll
    for (int mt = 0; mt < 4; mt++)
      af[mt] = *(const bf16x8*)&As[cur][(wm * 64 + mt * 16 + l16) * 32 + quad * 8];
#pragma unroll
    for (int nt = 0; nt < 4; nt++)
      bfr[nt] = *(const bf16x8*)&Bs[cur][(wn * 64 + nt * 16 + l16) * 32 + quad * 8];
#pragma unroll
    for (int mt = 0; mt < 4; mt++)
#pragma unroll
      for (int nt = 0; nt < 4; nt++)
        acc[mt][nt] = __builtin_amdgcn_mfma_f32_16x16x32_bf16(af[mt], bfr[nt], acc[mt][nt], 0, 0, 0);
    cur = nxt;
  }

  const int which = n0 / 768;
  const int rem0 = n0 % 768;
  bf16_t* dst = which == 0 ? Qo : (which == 1 ? Ko : Vo);
  const float qscale = which == 0 ? (0.125f * LOG2E) : 1.0f;
#pragma unroll
  for (int nt = 0; nt < 4; nt++) {
    const int cc = wn * 64 + nt * 16 + l16;
    const int rem = rem0 + cc;
    const int h = rem >> 6, hd = rem & 63;
    const float bv = bias[n0 + cc];
#pragma unroll
    for (int mt = 0; mt < 4; mt++)
#pragma unroll
      for (int r = 0; r < 4; r++) {
        const int gr = m0 + wm * 64 + mt * 16 + quad * 4 + r;
        const int bb = gr >> 11, s = gr & 2047;
        const float val = (acc[mt][nt][r] + bv) * qscale;
        dst[((size_t)((bb * NH + h) * SEQ + s)) * 64 + hd] = (bf16_t)val;
      }
  }
}

// ---------------------------------------------------------------- V transpose
__global__ __launch_bounds__(256) void vtrans_kernel(const bf16_t* __restrict__ V,
                                                     bf16_t* __restrict__ Vt) {
  __shared__ bf16_t tile[64][66];
  int bh = blockIdx.y, s0 = blockIdx.x * 64;
  int tid = threadIdx.x;
  int r = tid >> 4, c4 = (tid & 15) * 4;
  const bf16_t* src = V + (size_t)bh * SEQ * 64;
#pragma unroll
  for (int rr = r; rr < 64; rr += 16)
    *(bf16x4*)&tile[rr][c4] = *(const bf16x4*)&src[(size_t)(s0 + rr) * 64 + c4];
  __syncthreads();
  bf16_t* dst = Vt + (size_t)bh * 64 * SEQ;
#pragma unroll
  for (int hd = r; hd < 64; hd += 16) {
    bf16x4 o;
    o[0] = tile[c4 + 0][hd]; o[1] = tile[c4 + 1][hd];
    o[2] = tile[c4 + 2][hd]; o[3] = tile[c4 + 3][hd];
    *(bf16x4*)&dst[(size_t)hd * SEQ + s0 + c4] = o;
  }
}

// ---------------------------------------------------------------- flash attention
// R9 exact structure (56.2us known-good): 4 waves/block, grid (48,16),
// swapped-QK^T 32x32, triple-buffer LDS K/V via global_load_lds, pre-swizzled
// src + XOR reads, vmcnt(4), 1 barrier/tile, (256,3), T13 defer-max,
// ones-MFMA l-sum. R10's 8-wave variant regressed (384 blocks = 1.5/CU,
// parallel slack collapsed) — reverted.
__global__ __launch_bounds__(256, 3) void attn_kernel(
    const bf16_t* __restrict__ Q, const bf16_t* __restrict__ Kg,
    const bf16_t* __restrict__ Vt, bf16_t* __restrict__ Out) {
  __shared__ __align__(16) bf16_t Ks[3][64 * 64];  // 8KB per buf
  __shared__ __align__(16) bf16_t Vs[3][64 * 64];  // 8KB per buf (V^T layout)
  const int tid = threadIdx.x;
  const int w = tid >> 6, lane = tid & 63;
  const int l31 = lane & 31, hi = lane >> 5;
  const int bh = blockIdx.x;
  const int b = bh / NH, h = bh % NH;
  const int qt = (int)(gridDim.y - 1) - (int)blockIdx.y;  // heaviest first
  const int r0 = qt * 128 + w * 32;
  const int qrow = r0 + l31;
  const bf16_t* Qp = Q + (size_t)bh * SEQ * 64;
  const bf16_t* Kp = Kg + (size_t)bh * SEQ * 64;
  const bf16_t* Vp = Vt + (size_t)bh * 64 * SEQ;

  // Q fragment (B-operand): qf[kc][e] = Q[qrow][kc*16 + hi*8 + e]
  bf16x8 qf[4];
#pragma unroll
  for (int kc = 0; kc < 4; kc++)
    qf[kc] = *(const bf16x8*)&Qp[(size_t)qrow * 64 + kc * 16 + hi * 8];

  bf16x8 ones;
#pragma unroll
  for (int j = 0; j < 8; j++) ones[j] = (bf16_t)1.0f;

  float m_i = -1e30f;
  floatx16 accT[2];  // O^T: accT[dt][reg] = O[qrow][dt*32 + rowfn(reg,hi)]
  accT[0] = (floatx16)(0.f);
  accT[1] = (floatx16)(0.f);
  floatx16 zl = (floatx16)(0.f);  // l-sum via ones-MFMA (all rows identical)

  const int nt_w = (r0 >> 6) + 1;          // this wave's tile count
  const int ntmax = 2 * qt + 2;            // block's max tile count (w=3)

  // staging geometry: round r covers LDS bytes [r*4096 + w*1024 + lane*16, +16)
  int srow[2], scolb[2];
#pragma unroll
  for (int r = 0; r < 2; r++) {
    int off = r * 4096 + w * 1024 + lane * 16;
    int row = off >> 7;
    srow[r] = row;
    scolb[r] = (off & 127) ^ ((row & 7) << 4);
  }

  auto stage = [&](int buf, int kt) {
    const int kbase = kt * 64;
#pragma unroll
    for (int r = 0; r < 2; r++) {
      gload_lds16(Kp + (size_t)(kbase + srow[r]) * 64 + (scolb[r] >> 1),
                  &Ks[buf][r * 2048 + w * 512]);
      gload_lds16(Vp + (size_t)srow[r] * SEQ + kbase + (scolb[r] >> 1),
                  &Vs[buf][r * 2048 + w * 512]);
    }
  };

  const int swz = (l31 & 7) << 4;  // read-side XOR (row&7 == l31&7 for all frags)

  stage(0, 0);  // prologue: tile 0 -> buf 0 (4 loads in flight)

  int cur = 0;
  for (int kt = 0; kt < ntmax; kt++) {
    const int nxt = (cur == 2) ? 0 : cur + 1;
    if (kt + 1 < ntmax) {
      stage(nxt, kt + 1);
      asm volatile("s_waitcnt vmcnt(4)" ::: "memory");  // buf[cur] landed
    } else {
      asm volatile("s_waitcnt vmcnt(0)" ::: "memory");
    }
    __builtin_amdgcn_s_barrier();  // all waves' stage of buf[cur] visible

    if (kt < nt_w) {
      const int kbase = kt * 64;
      const bf16_t* Kb = Ks[cur];
      const bf16_t* Vb = Vs[cur];
      // ---- QK^T (swapped): st[kt2][r] = S[qrow][kbase+kt2*32+(r&3)+8*(r>>2)+4*hi]
      floatx16 st[2];
#pragma unroll
      for (int kt2 = 0; kt2 < 2; kt2++) {
        const int row = kt2 * 32 + l31;
        floatx16 z = (floatx16)(0.f);
#pragma unroll
        for (int kc = 0; kc < 4; kc++) {
          bf16x8 kfr = *(const bf16x8*)&Kb[row * 64 + (((kc * 32 + hi * 16) ^ swz) >> 1)];
          z = __builtin_amdgcn_mfma_f32_32x32x16_bf16(kfr, qf[kc], z, 0, 0, 0);
        }
        st[kt2] = z;
      }
      // ---- causal mask (only on this wave's last tile)
      if (kt == nt_w - 1) {
#pragma unroll
        for (int kt2 = 0; kt2 < 2; kt2++)
#pragma unroll
          for (int r = 0; r < 16; r++) {
            int key = kbase + kt2 * 32 + (r & 3) + 8 * (r >> 2) + 4 * hi;
            if (key > qrow) st[kt2][r] = -1e30f;
          }
      }
      // ---- online softmax (exp2 domain), T13 defer-max
      float mloc = -1e30f;
#pragma unroll
      for (int kt2 = 0; kt2 < 2; kt2++)
#pragma unroll
        for (int r = 0; r < 16; r++) mloc = fmaxf(mloc, st[kt2][r]);
      mloc = fmaxf(mloc, __shfl_xor(mloc, 32));
      if (!__all((int)(mloc - m_i <= 8.f))) {  // rescale path (rare after tile 0)
        const float mnew = fmaxf(m_i, mloc);
        const float al = __builtin_amdgcn_exp2f(m_i - mnew);
        m_i = mnew;
#pragma unroll
        for (int r = 0; r < 16; r++) zl[r] *= al;
#pragma unroll
        for (int dt = 0; dt < 2; dt++)
#pragma unroll
          for (int r = 0; r < 16; r++) accT[dt][r] *= al;
      }
#pragma unroll
      for (int kt2 = 0; kt2 < 2; kt2++)
#pragma unroll
        for (int r = 0; r < 16; r++)
          st[kt2][r] = __builtin_amdgcn_exp2f(st[kt2][r] - m_i);  // <= 2^8
      // ---- P pack + half-wave exchange -> B-fragments; PV + l-sum MFMAs
#pragma unroll
      for (int kt2 = 0; kt2 < 2; kt2++) {
        unsigned int wds[8];
#pragma unroll
        for (int j = 0; j < 8; j++) wds[j] = pack2(st[kt2][2 * j], st[kt2][2 * j + 1]);
        unsigned int x0 = (unsigned int)__shfl_xor((int)(hi ? wds[0] : wds[2]), 32);
        unsigned int x1 = (unsigned int)__shfl_xor((int)(hi ? wds[1] : wds[3]), 32);
        unsigned int x2 = (unsigned int)__shfl_xor((int)(hi ? wds[4] : wds[6]), 32);
        unsigned int x3 = (unsigned int)__shfl_xor((int)(hi ? wds[5] : wds[7]), 32);
        u32x4 f0 = hi ? (u32x4){x0, x1, wds[2], wds[3]} : (u32x4){wds[0], wds[1], x0, x1};
        u32x4 f1 = hi ? (u32x4){x2, x3, wds[6], wds[7]} : (u32x4){wds[4], wds[5], x2, x3};
        bf16x8 pf0 = __builtin_bit_cast(bf16x8, f0);
        bf16x8 pf1 = __builtin_bit_cast(bf16x8, f1);
        zl = __builtin_amdgcn_mfma_f32_32x32x16_bf16(ones, pf0, zl, 0, 0, 0);
        zl = __builtin_amdgcn_mfma_f32_32x32x16_bf16(ones, pf1, zl, 0, 0, 0);
#pragma unroll
        for (int dt = 0; dt < 2; dt++) {
          const int vrow = dt * 32 + l31;
          bf16x8 v0 = *(const bf16x8*)&Vb[vrow * 64 + (((kt2 * 64 + hi * 16) ^ swz) >> 1)];
          bf16x8 v1 = *(const bf16x8*)&Vb[vrow * 64 + (((kt2 * 64 + 32 + hi * 16) ^ swz) >> 1)];
          accT[dt] = __builtin_amdgcn_mfma_f32_32x32x16_bf16(v0, pf0, accT[dt], 0, 0, 0);
          accT[dt] = __builtin_amdgcn_mfma_f32_32x32x16_bf16(v1, pf1, accT[dt], 0, 0, 0);
        }
      }
    }
    cur = nxt;
  }

  // ---- epilogue: lane-local divide (zl rows all identical), bf16x4 stores
  const float inv_l = 1.0f / zl[0];
#pragma unroll
  for (int dt = 0; dt < 2; dt++)
#pragma unroll
    for (int g = 0; g < 4; g++) {
      bf16x4 o;
#pragma unroll
      for (int j = 0; j < 4; j++) o[j] = (bf16_t)(accT[dt][4 * g + j] * inv_l);
      int d = dt * 32 + 8 * g + 4 * hi;
      *(bf16x4*)&Out[((size_t)(b * SEQ + qrow)) * DM + h * 64 + d] = o;
    }
}

// ---------------------------------------------------------------- out-proj GEMM
// Same triple-buffer single-barrier upgrade as gemm_qkv.
__global__ __launch_bounds__(256) void gemm_proj_kernel(
    const bf16_t* __restrict__ A, const bf16_t* __restrict__ BT,
    const float* __restrict__ bias, float* __restrict__ out) {
  const int K = 768;
  const int NT = 24;
  __shared__ __align__(16) bf16_t As[3][128 * 32];
  __shared__ __align__(16) bf16_t Bs[3][128 * 32];
  const int m0 = blockIdx.x * 128, n0 = blockIdx.y * 128;
  const int tid = threadIdx.x;
  const int w = tid >> 6, lane = tid & 63, quad = lane >> 4, l16 = lane & 15;
  const int wm = w >> 1, wn = w & 1;
  const int ldrow = w * 32;
  const int grow = lane >> 2;
  const int gcol = (lane & 3) * 8;

  floatx4 acc[4][4];
#pragma unroll
  for (int mt = 0; mt < 4; mt++)
#pragma unroll
    for (int nt = 0; nt < 4; nt++) acc[mt][nt] = (floatx4)(0.f);

  const bf16_t* ga0 = A + (size_t)(m0 + ldrow) * K;
  const bf16_t* gb0 = BT + (size_t)(n0 + ldrow) * K;

  auto stage = [&](int buf, int k0) {
    gload_lds16(ga0 + (size_t)grow * K + k0 + gcol,        &As[buf][ldrow * 32]);
    gload_lds16(ga0 + (size_t)(grow + 16) * K + k0 + gcol, &As[buf][(ldrow + 16) * 32]);
    gload_lds16(gb0 + (size_t)grow * K + k0 + gcol,        &Bs[buf][ldrow * 32]);
    gload_lds16(gb0 + (size_t)(grow + 16) * K + k0 + gcol, &Bs[buf][(ldrow + 16) * 32]);
  };

  stage(0, 0);
  int cur = 0;
  for (int t = 0; t < NT; t++) {
    const int nxt = (cur == 2) ? 0 : cur + 1;
    if (t + 1 < NT) {
      stage(nxt, (t + 1) * 32);
      asm volatile("s_waitcnt vmcnt(4)" ::: "memory");
    } else {
      asm volatile("s_waitcnt vmcnt(0)" ::: "memory");
    }
    __builtin_amdgcn_s_barrier();

    bf16x8 af[4], bfr[4];
#pragma unroll
    for (int mt = 0; mt < 4; mt++)
      af[mt] = *(const bf16x8*)&As[cur][(wm * 64 + mt * 16 + l16) * 32 + quad * 8];
#pragma unroll
    for (int nt = 0; nt < 4; nt++)
      bfr[nt] = *(const bf16x8*)&Bs[cur][(wn * 64 + nt * 16 + l16) * 32 + quad * 8];
#pragma unroll
    for (int mt = 0; mt < 4; mt++)
#pragma unroll
      for (int nt = 0; nt < 4; nt++)
        acc[mt][nt] = __builtin_amdgcn_mfma_f32_16x16x32_bf16(af[mt], bfr[nt], acc[mt][nt], 0, 0, 0);
    cur = nxt;
  }

#pragma unroll
  for (int nt = 0; nt < 4; nt++) {
    const int gc = n0 + wn * 64 + nt * 16 + l16;
    const float bv = bias[gc];
#pragma unroll
    for (int mt = 0; mt < 4; mt++)
#pragma unroll
      for (int r = 0; r < 4; r++) {
        const int gr = m0 + wm * 64 + mt * 16 + quad * 4 + r;
        out[(size_t)gr * 768 + gc] = acc[mt][nt][r] + bv;
      }
  }
}

// ---------------------------------------------------------------- launch
extern "C" void kernel_launch(void* const* d_in, const int* in_sizes, int n_in,
                              void* d_out, int out_size, void* d_ws, size_t ws_size,
                              hipStream_t stream) {
  const float* x      = (const float*)d_in[0];
  const float* w_qkv  = (const float*)d_in[1];
  const float* b_qkv  = (const float*)d_in[2];
  const float* w_proj = (const float*)d_in[3];
  const float* b_proj = (const float*)d_in[4];
  float* out = (float*)d_out;
  char* ws = (char*)d_ws;

  // workspace layout (all 16B-aligned), total 67,633,152 B
  bf16_t* xb     = (bf16_t*)(ws + 0);         // 8192*768  bf16 (dead after gemm_qkv)
  bf16_t* wqkvT  = (bf16_t*)(ws + 12582912);  // 2304*768  bf16
  bf16_t* wprojT = (bf16_t*)(ws + 16121856);  //  768*768  bf16
  bf16_t* q      = (bf16_t*)(ws + 17301504);  // [4][12][2048][64] bf16
  bf16_t* k      = (bf16_t*)(ws + 29884416);
  bf16_t* v      = (bf16_t*)(ws + 42467328);
  bf16_t* ao     = (bf16_t*)(ws + 55050240);  // [8192][768] bf16
  bf16_t* vt     = xb;                        // aliases xb: [4][12][64][2048] bf16

  prep_kernel<<<8448, 256, 0, stream>>>(x, xb, w_qkv, wqkvT, w_proj, wprojT);
  gemm_qkv_kernel<<<dim3(64, 18), 256, 0, stream>>>(xb, wqkvT, b_qkv, q, k, v);
  vtrans_kernel<<<dim3(32, 48), 256, 0, stream>>>(v, vt);
  attn_kernel<<<dim3(48, 16), 256, 0, stream>>>(q, k, vt, ao);
  gemm_proj_kernel<<<dim3(64, 6), 256, 0, stream>>>(ao, wprojT, b_proj, out);
}